// Round 5
// baseline (377.231 us; speedup 1.0000x reference)
//
#include <hip/hip_runtime.h>
#include <math.h>

#define BB 8
#define NN 65536
#define CC 80
#define TT 32
#define MINPOS 16
#define TIECAP 4096

__device__ __forceinline__ float frcp(float x) { return __builtin_amdgcn_rcpf(x); }

// ------------------------------------------------------------------
// K1 (k_prep): decode + IoU max only + per-image posCnt + coarse
// 512-bin hist of miou float bits [31:21]. Grid (N/256, B).
// ------------------------------------------------------------------
__global__ __launch_bounds__(256) void k_prep(
    const float* __restrict__ reg, const float* __restrict__ anchors,
    const float* __restrict__ tboxes,
    float* __restrict__ miou_out, unsigned* __restrict__ gHist,
    int* __restrict__ posCnt)
{
    const int b   = blockIdx.y;
    const int tid = threadIdx.x;
    const int a   = blockIdx.x * 256 + tid;

    __shared__ float4 tb[TT];
    __shared__ float  tareaE[TT];
    __shared__ unsigned lh[512];
    __shared__ int    s_pc;

    if (tid < TT) {
        float4 t = ((const float4*)(tboxes + (size_t)b * TT * 4))[tid];
        tb[tid] = t;
        tareaE[tid] = (t.z - t.x) * (t.w - t.y) + 1e-6f;
    }
    lh[tid] = 0u; lh[tid + 256] = 0u;
    if (tid == 0) s_pc = 0;
    __syncthreads();

    float4 r  = ((const float4*)reg)[(size_t)b * NN + a];
    float4 an = ((const float4*)anchors)[a];
    float aw = an.z - an.x, ah = an.w - an.y;
    float acx = an.x + 0.5f * aw, acy = an.y + 0.5f * ah;
    float cx = r.x * aw + acx, cy = r.y * ah + acy;
    float w = expf(r.z) * aw, hh = expf(r.w) * ah;
    float dx0 = cx - 0.5f * w, dy0 = cy - 0.5f * hh;
    float dx1 = cx + 0.5f * w, dy1 = cy + 0.5f * hh;
    float areaA = (dx1 - dx0) * (dy1 - dy0);

    float mi = 0.0f;
    #pragma unroll 8
    for (int t = 0; t < TT; ++t) {
        float4 bx = tb[t];
        float ltx = fmaxf(dx0, bx.x), lty = fmaxf(dy0, bx.y);
        float rbx = fminf(dx1, bx.z), rby = fminf(dy1, bx.w);
        float iw = fmaxf(rbx - ltx, 0.0f), ih = fmaxf(rby - lty, 0.0f);
        float inter = iw * ih;
        float den = areaA + tareaE[t] - inter;
        float iou = inter * frcp(den);
        mi = fmaxf(mi, iou);
    }

    miou_out[(size_t)b * NN + a] = mi;
    atomicAdd(&lh[__float_as_uint(mi) >> 21], 1u);   // mi in [0,1] -> bin <= 508
    unsigned long long bal = __ballot(mi >= 0.5f);
    if ((tid & 63) == 0) atomicAdd(&s_pc, __popcll(bal));
    __syncthreads();

    if (lh[tid])       atomicAdd(&gHist[b * 512 + tid],       lh[tid]);
    if (lh[tid + 256]) atomicAdd(&gHist[b * 512 + tid + 256], lh[tid + 256]);
    if (tid == 0) atomicAdd(&posCnt[b], s_pc);
}

// ------------------------------------------------------------------
// scan over an LDS histogram: find bin d s.t. (count strictly above d)
// < need <= (count above + h[d]). sh_s[2]=need on entry; writes
// sh_s[0]=bin, sh_s[1]=count strictly above. Proven R1..R4.
// ------------------------------------------------------------------
__device__ __forceinline__ void scan_hist64(unsigned* hist, int NB, int tid, int* sh_s)
{
    if (tid < 64) {
        const int cs = NB / 64;
        const int base = tid * cs;
        int csum = 0;
        for (int j = 0; j < cs; ++j) csum += (int)hist[base + j];
        int sfx = csum;
        #pragma unroll
        for (int off = 1; off < 64; off <<= 1) {
            int o = __shfl_down(sfx, off);
            if (tid + off < 64) sfx += o;
        }
        const int excl = sfx - csum;
        const int need = sh_s[2];
        int acc = excl;
        for (int j = cs - 1; j >= 0; --j) {
            int hcnt = (int)hist[base + j];
            int S = acc + hcnt;
            if (acc < need && S >= need) { sh_s[0] = base + j; sh_s[1] = acc; }
            acc = S;
        }
    }
}

// ------------------------------------------------------------------
// K2 (k_finehist): grid-parallel fine histogram (bits [20:10]) of the
// values inside the coarse pivot bin. Grid (32, B).
// ------------------------------------------------------------------
__global__ __launch_bounds__(256) void k_finehist(
    const float* __restrict__ miou_all, const unsigned* __restrict__ gHist,
    const int* __restrict__ posCnt, unsigned* __restrict__ fineHist)
{
    const int b = blockIdx.y;
    const int tid = threadIdx.x;
    const int pc = posCnt[b];
    if (pc < MINPOS) return;                    // fallback path handles it
    const int np = pc;
    int kk = NN - np; if (4 * np < kk) kk = 4 * np;

    __shared__ unsigned hist[512];
    __shared__ int sh_s[3];
    hist[tid]       = (tid <= 503)       ? gHist[b * 512 + tid]       : 0u;
    hist[tid + 256] = (tid + 256 <= 503) ? gHist[b * 512 + tid + 256] : 0u;
    if (tid == 0) sh_s[2] = kk;
    __syncthreads();
    scan_hist64(hist, 512, tid, sh_s);
    __syncthreads();
    const unsigned pivotBin = (unsigned)sh_s[0];

    const float* miou = miou_all + (size_t)b * NN;
    const int base = blockIdx.x * 2048;
    for (int i = base + tid; i < base + 2048; i += 256) {
        unsigned u = __float_as_uint(miou[i]);
        if ((u >> 21) == pivotBin)
            atomicAdd(&fineHist[b * 2048 + ((u >> 10) & 2047u)], 1u);
    }
}

// ------------------------------------------------------------------
// K3 (k_compact): grid-parallel selection + compaction; the LAST block
// per image (done-counter) additionally ranks the pivot-bin ties and
// appends accepted negatives (absorbs former k_tierank). Grid (32, B).
// ------------------------------------------------------------------
__global__ __launch_bounds__(256) void k_compact(
    const float* __restrict__ reg, const float* __restrict__ anchors,
    const float* __restrict__ tboxes, const int* __restrict__ tlabels,
    const float* __restrict__ miou_all,
    const unsigned* __restrict__ gHist, const unsigned* __restrict__ fineHist,
    const int* __restrict__ posCnt,
    unsigned* __restrict__ list_all, int* __restrict__ listCnt,
    unsigned* __restrict__ tieU_all, int* __restrict__ tieI_all,
    int* __restrict__ tieCnt, int* __restrict__ doneC,
    int* __restrict__ numpos, int* __restrict__ knum, float* __restrict__ accum)
{
    const int b = blockIdx.y;
    const int tid = threadIdx.x;
    const int pc = posCnt[b];
    if (pc < MINPOS) return;                    // fallback path handles it
    const int np = pc;
    int kk = NN - np; if (4 * np < kk) kk = 4 * np;

    __shared__ float4 tb[TT];
    __shared__ float  tareaE[TT];
    __shared__ int    tl[TT];
    __shared__ unsigned hist[2048];
    __shared__ unsigned lbuf[2048];
    __shared__ unsigned tu[TIECAP];
    __shared__ int      ti[TIECAP];
    __shared__ int sh_s[3];
    __shared__ int sh_cnt, sh_base, sh_last;
    __shared__ float wred[4];

    if (tid < TT) {
        float4 t = ((const float4*)(tboxes + (size_t)b * TT * 4))[tid];
        tb[tid] = t;
        tareaE[tid] = (t.z - t.x) * (t.w - t.y) + 1e-6f;
        tl[tid] = tlabels[b * TT + tid];
    }
    // coarse pivot
    hist[tid]       = (tid <= 503)       ? gHist[b * 512 + tid]       : 0u;
    hist[tid + 256] = (tid + 256 <= 503) ? gHist[b * 512 + tid + 256] : 0u;
    if (tid == 0) { sh_s[2] = kk; sh_cnt = 0; }
    __syncthreads();
    scan_hist64(hist, 512, tid, sh_s);
    __syncthreads();
    const unsigned pivotBin = (unsigned)sh_s[0];
    const int needB = kk - sh_s[1];
    __syncthreads();
    // fine pivot
    for (int k = tid; k < 2048; k += 256) hist[k] = fineHist[b * 2048 + k];
    if (tid == 0) sh_s[2] = needB;
    __syncthreads();
    scan_hist64(hist, 2048, tid, sh_s);
    __syncthreads();
    const unsigned pivot22 = (pivotBin << 11) | (unsigned)sh_s[0];
    const int rem = needB - sh_s[1];     // ties (value desc, idx asc) to accept

    float accR = 0.0f;
    const float* miou = miou_all + (size_t)b * NN;
    const int base = blockIdx.x * 2048;
    for (int i = base + tid; i < base + 2048; i += 256) {
        float v = miou[i];
        unsigned u = __float_as_uint(v);
        if (v >= 0.5f) {
            // recompute argmax (bit-identical IoU to k_prep) + sl1 + label
            float4 r  = ((const float4*)reg)[(size_t)b * NN + i];
            float4 an = ((const float4*)anchors)[i];
            float aw = an.z - an.x, ah = an.w - an.y;
            float acx = an.x + 0.5f * aw, acy = an.y + 0.5f * ah;
            float cx = r.x * aw + acx, cy = r.y * ah + acy;
            float w = expf(r.z) * aw, hh2 = expf(r.w) * ah;
            float dx0 = cx - 0.5f * w, dy0 = cy - 0.5f * hh2;
            float dx1 = cx + 0.5f * w, dy1 = cy + 0.5f * hh2;
            float areaA = (dx1 - dx0) * (dy1 - dy0);
            float mi = 0.0f; int mix = 0;
            #pragma unroll 8
            for (int t = 0; t < TT; ++t) {
                float4 bx = tb[t];
                float ltx = fmaxf(dx0, bx.x), lty = fmaxf(dy0, bx.y);
                float rbx = fminf(dx1, bx.z), rby = fminf(dy1, bx.w);
                float iw = fmaxf(rbx - ltx, 0.0f), ih = fmaxf(rby - lty, 0.0f);
                float inter = iw * ih;
                float den = areaA + tareaE[t] - inter;
                float iou = inter * frcp(den);
                if (iou > mi) { mi = iou; mix = t; }
            }
            float4 gt = tb[mix];
            float gw = gt.z - gt.x, gh = gt.w - gt.y;
            float gcx = gt.x + 0.5f * gw, gcy = gt.y + 0.5f * gh;
            float t0 = (gcx - acx) / (aw + 1e-6f);
            float t1 = (gcy - acy) / (ah + 1e-6f);
            float t2 = logf(gw / (aw + 1e-6f));
            float t3 = logf(gh / (ah + 1e-6f));
            float d0 = fabsf(r.x - t0), d1 = fabsf(r.y - t1);
            float d2 = fabsf(r.z - t2), d3 = fabsf(r.w - t3);
            accR += (d0 < 1.0f ? 0.5f * d0 * d0 : d0 - 0.5f)
                  + (d1 < 1.0f ? 0.5f * d1 * d1 : d1 - 0.5f)
                  + (d2 < 1.0f ? 0.5f * d2 * d2 : d2 - 0.5f)
                  + (d3 < 1.0f ? 0.5f * d3 * d3 : d3 - 0.5f);
            int t4 = atomicAdd(&sh_cnt, 1);
            lbuf[t4] = (unsigned)i | 0x10000u | ((unsigned)tl[mix] << 17);
        } else {
            unsigned p = u >> 10;
            if (p > pivot22) {
                int t = atomicAdd(&sh_cnt, 1);
                lbuf[t] = (unsigned)i;
            } else if (p == pivot22) {
                int t = atomicAdd(&tieCnt[b], 1);
                if (t < TIECAP) {
                    tieU_all[b * TIECAP + t] = u;
                    tieI_all[b * TIECAP + t] = i;
                }
            }
        }
    }
    __syncthreads();
    const int cnt = sh_cnt;
    if (tid == 0) sh_base = atomicAdd(&listCnt[b], cnt);
    __syncthreads();
    unsigned* list = list_all + (size_t)b * NN;
    for (int k = tid; k < cnt; k += 256) list[sh_base + k] = lbuf[k];

    #pragma unroll
    for (int off = 32; off > 0; off >>= 1) accR += __shfl_down(accR, off);
    const int lane = tid & 63, wave = tid >> 6;
    if (lane == 0) wred[wave] = accR;
    __syncthreads();
    if (tid == 0) {
        atomicAdd(&accum[b * 3 + 2], wred[0] + wred[1] + wred[2] + wred[3]);
        if (blockIdx.x == 0) { numpos[b] = np; knum[b] = kk; }
    }

    // ---- last block for this image ranks the ties (absorbed k_tierank) ----
    __threadfence();
    if (tid == 0) sh_last = atomicAdd(&doneC[b], 1);
    __syncthreads();
    if (sh_last == 31) {
        int c = tieCnt[b]; if (c > TIECAP) c = TIECAP;
        for (int k = tid; k < c; k += 256) {
            tu[k] = tieU_all[b * TIECAP + k];
            ti[k] = tieI_all[b * TIECAP + k];
        }
        __syncthreads();
        for (int t = tid; t < c; t += 256) {
            unsigned ut = tu[t]; int it = ti[t];
            int rank = 0;
            for (int j = 0; j < c; ++j) {
                unsigned uj = tu[j]; int ij = ti[j];
                rank += (uj > ut || (uj == ut && ij < it)) ? 1 : 0;
            }
            if (rank < rem) {
                int p = atomicAdd(&listCnt[b], 1);
                list[p] = (unsigned)it;
            }
        }
    }
}

// R1-proven 3-round radix select (fallback path only).
__device__ __forceinline__ void radix_select(
    const float* __restrict__ vals, const unsigned char* __restrict__ mask,
    int mode, int kk, int tid,
    unsigned* hist, int* sh_s, unsigned* sh_u)
{
    if (tid == 0) { sh_u[0] = 0u; sh_u[1] = 0u; sh_s[2] = kk; }
    __syncthreads();
    #pragma unroll
    for (int rnd = 0; rnd < 3; ++rnd) {
        const int sh = (rnd == 0) ? 21 : ((rnd == 1) ? 10 : 0);
        const int NB = (rnd == 2) ? 1024 : 2048;
        hist[tid] = 0u; hist[tid + 1024] = 0u;
        __syncthreads();
        const unsigned pref = sh_u[0], pmask = sh_u[1];
        for (int i = tid; i < NN; i += 1024) {
            bool c = (mode == 0) ? true : (mask[i] != (unsigned char)1);
            if (c) {
                unsigned u = __float_as_uint(vals[i]);
                if ((u & pmask) == pref)
                    atomicAdd(&hist[(u >> sh) & (unsigned)(NB - 1)], 1u);
            }
        }
        __syncthreads();
        scan_hist64(hist, NB, tid, sh_s);
        __syncthreads();
        if (tid == 0) {
            sh_u[0] |= ((unsigned)sh_s[0]) << sh;
            sh_u[1] |= ((unsigned)(NB - 1)) << sh;
            sh_s[2] -= sh_s[1];
        }
        __syncthreads();
    }
}

// ------------------------------------------------------------------
// K4 (k_fallback): full slow path, only if posCnt[b] < MINPOS (never
// hit with this data — early-returns). Grid (B) x 1024.
// ------------------------------------------------------------------
__global__ __launch_bounds__(1024) void k_fallback(
    const float* __restrict__ reg, const float* __restrict__ anchors,
    const float* __restrict__ tboxes, const int* __restrict__ tlabels,
    const float* __restrict__ miou_all, unsigned char* __restrict__ mask_all,
    const int* __restrict__ posCnt,
    unsigned* __restrict__ list_all, int* __restrict__ listCnt,
    int* __restrict__ numpos, int* __restrict__ knum, float* __restrict__ accum)
{
    const int b = blockIdx.x;
    const int tid = threadIdx.x;
    if (posCnt[b] >= MINPOS) return;

    const float* miou = miou_all + (size_t)b * NN;
    unsigned char* mask = mask_all + (size_t)b * NN;
    unsigned* list = list_all + (size_t)b * NN;

    __shared__ float4 tb[TT];
    __shared__ float  tareaE[TT];
    __shared__ int    tl[TT];
    __shared__ unsigned hist[2048];
    __shared__ int sh_s[3];
    __shared__ unsigned sh_u[2];
    __shared__ int wtot[16];
    __shared__ int sh_ties;
    __shared__ float wred[16];

    if (tid < TT) {
        float4 t = ((const float4*)(tboxes + (size_t)b * TT * 4))[tid];
        tb[tid] = t;
        tareaE[tid] = (t.z - t.x) * (t.w - t.y) + 1e-6f;
        tl[tid] = tlabels[b * TT + tid];
    }
    __syncthreads();

    radix_select(miou, mask, 0, MINPOS, tid, hist, sh_s, sh_u);
    {
        const unsigned vb = sh_u[0];
        const int rem = sh_s[2];
        if (tid == 0) sh_ties = 0;
        __syncthreads();
        for (int base = 0; base < NN; base += 1024) {
            const int i = base + tid;
            const unsigned u = __float_as_uint(miou[i]);
            const bool tie = (u == vb);
            unsigned long long bal = __ballot(tie);
            const int wave = tid >> 6, lane = tid & 63;
            if (lane == 0) wtot[wave] = __popcll(bal);
            __syncthreads();
            int wexcl = 0;
            for (int wv = 0; wv < wave; ++wv) wexcl += wtot[wv];
            const int myexcl = sh_ties + wexcl + __popcll(bal & ((1ull << lane) - 1ull));
            const bool sel = (u > vb) || (tie && myexcl < rem);
            mask[i] = sel ? (unsigned char)1 : (unsigned char)0;
            __syncthreads();
            if (tid == 0) { int ts = 0; for (int wv = 0; wv < 16; ++wv) ts += wtot[wv]; sh_ties += ts; }
            __syncthreads();
        }
    }
    const int np = MINPOS;
    int kk = NN - np; if (4 * np < kk) kk = 4 * np;
    radix_select(miou, mask, 2, kk, tid, hist, sh_s, sh_u);
    {
        const unsigned vb = sh_u[0];
        const int rem = sh_s[2];
        if (tid == 0) sh_ties = 0;
        __syncthreads();
        for (int base = 0; base < NN; base += 1024) {
            const int i = base + tid;
            const unsigned u = __float_as_uint(miou[i]);
            const bool pos = (mask[i] == (unsigned char)1);
            const bool cand = !pos;
            const bool tie = cand && (u == vb);
            unsigned long long bal = __ballot(tie);
            const int wave = tid >> 6, lane = tid & 63;
            if (lane == 0) wtot[wave] = __popcll(bal);
            __syncthreads();
            int wexcl = 0;
            for (int wv = 0; wv < wave; ++wv) wexcl += wtot[wv];
            const int myexcl = sh_ties + wexcl + __popcll(bal & ((1ull << lane) - 1ull));
            const bool neg = cand && ((u > vb) || (tie && myexcl < rem));
            mask[i] = pos ? (unsigned char)1 : (neg ? (unsigned char)2 : (unsigned char)0);
            __syncthreads();
            if (tid == 0) { int ts = 0; for (int wv = 0; wv < 16; ++wv) ts += wtot[wv]; sh_ties += ts; }
            __syncthreads();
        }
    }

    float accR = 0.0f;
    for (int i = tid; i < NN; i += 1024) {
        unsigned char m = mask[i];
        if (m == (unsigned char)1) {
            float4 r  = ((const float4*)reg)[(size_t)b * NN + i];
            float4 an = ((const float4*)anchors)[i];
            float aw = an.z - an.x, ah = an.w - an.y;
            float acx = an.x + 0.5f * aw, acy = an.y + 0.5f * ah;
            float cx = r.x * aw + acx, cy = r.y * ah + acy;
            float w = expf(r.z) * aw, hh2 = expf(r.w) * ah;
            float dx0 = cx - 0.5f * w, dy0 = cy - 0.5f * hh2;
            float dx1 = cx + 0.5f * w, dy1 = cy + 0.5f * hh2;
            float areaA = (dx1 - dx0) * (dy1 - dy0);
            float mi = 0.0f; int mix = 0;
            for (int t = 0; t < TT; ++t) {
                float4 bx = tb[t];
                float ltx = fmaxf(dx0, bx.x), lty = fmaxf(dy0, bx.y);
                float rbx = fminf(dx1, bx.z), rby = fminf(dy1, bx.w);
                float iw = fmaxf(rbx - ltx, 0.0f), ih = fmaxf(rby - lty, 0.0f);
                float inter = iw * ih;
                float den = areaA + tareaE[t] - inter;
                float iou = inter * frcp(den);
                if (iou > mi) { mi = iou; mix = t; }
            }
            float4 gt = tb[mix];
            float gw = gt.z - gt.x, gh = gt.w - gt.y;
            float gcx = gt.x + 0.5f * gw, gcy = gt.y + 0.5f * gh;
            float t0 = (gcx - acx) / (aw + 1e-6f);
            float t1 = (gcy - acy) / (ah + 1e-6f);
            float t2 = logf(gw / (aw + 1e-6f));
            float t3 = logf(gh / (ah + 1e-6f));
            float d0 = fabsf(r.x - t0), d1 = fabsf(r.y - t1);
            float d2 = fabsf(r.z - t2), d3 = fabsf(r.w - t3);
            accR += (d0 < 1.0f ? 0.5f * d0 * d0 : d0 - 0.5f)
                  + (d1 < 1.0f ? 0.5f * d1 * d1 : d1 - 0.5f)
                  + (d2 < 1.0f ? 0.5f * d2 * d2 : d2 - 0.5f)
                  + (d3 < 1.0f ? 0.5f * d3 * d3 : d3 - 0.5f);
            int t = atomicAdd(&listCnt[b], 1);
            list[t] = (unsigned)i | 0x10000u | ((unsigned)tl[mix] << 17);
        } else if (m == (unsigned char)2) {
            int t = atomicAdd(&listCnt[b], 1);
            list[t] = (unsigned)i;
        }
    }

    #pragma unroll
    for (int off = 32; off > 0; off >>= 1) accR += __shfl_down(accR, off);
    const int lane = tid & 63, wave = tid >> 6;
    if (lane == 0) wred[wave] = accR;
    __syncthreads();
    if (tid == 0) {
        float sR = 0.0f;
        for (int w = 0; w < 16; ++w) sR += wred[w];
        accum[b * 3 + 2] = sR;
        numpos[b] = np;
        knum[b] = kk;
    }
}

// ------------------------------------------------------------------
// K5 (k_cls2): gather logsumexp ONLY for selected anchors; the LAST
// block of the whole grid finalizes the 4 scalars (absorbs k_finalize).
// 4 threads/entry; grid (256, B).
// ------------------------------------------------------------------
__global__ __launch_bounds__(256) void k_cls2(
    const float* __restrict__ cls, const unsigned* __restrict__ list_all,
    const int* __restrict__ listCnt, float* __restrict__ accum,
    const int* __restrict__ numpos, const int* __restrict__ knum,
    int* __restrict__ doneF, float* __restrict__ out)
{
    const int b   = blockIdx.y;
    const int n   = listCnt[b];
    const int al  = threadIdx.x >> 2;
    const int sub = threadIdx.x & 3;
    const unsigned* list = list_all + (size_t)b * NN;

    float aP = 0.0f, aN = 0.0f;
    for (int e = blockIdx.x * 64 + al; e < n; e += gridDim.x * 64) {
        unsigned ent = list[e];
        int a = (int)(ent & 0xFFFFu);
        size_t row = (size_t)b * NN + a;
        const float4* rowp = (const float4*)(cls + row * CC);
        float4 v0 = rowp[sub];
        float4 v1 = rowp[sub + 4];
        float4 v2 = rowp[sub + 8];
        float4 v3 = rowp[sub + 12];
        float4 v4 = rowp[sub + 16];
        float mx = fmaxf(fmaxf(fmaxf(v0.x, v0.y), fmaxf(v0.z, v0.w)),
                   fmaxf(fmaxf(fmaxf(v1.x, v1.y), fmaxf(v1.z, v1.w)),
                   fmaxf(fmaxf(fmaxf(v2.x, v2.y), fmaxf(v2.z, v2.w)),
                   fmaxf(fmaxf(fmaxf(v3.x, v3.y), fmaxf(v3.z, v3.w)),
                         fmaxf(fmaxf(v4.x, v4.y), fmaxf(v4.z, v4.w))))));
        float sm = expf(v0.x - mx) + expf(v0.y - mx) + expf(v0.z - mx) + expf(v0.w - mx)
                 + expf(v1.x - mx) + expf(v1.y - mx) + expf(v1.z - mx) + expf(v1.w - mx)
                 + expf(v2.x - mx) + expf(v2.y - mx) + expf(v2.z - mx) + expf(v2.w - mx)
                 + expf(v3.x - mx) + expf(v3.y - mx) + expf(v3.z - mx) + expf(v3.w - mx)
                 + expf(v4.x - mx) + expf(v4.y - mx) + expf(v4.z - mx) + expf(v4.w - mx);
        #pragma unroll
        for (int off = 1; off < 4; off <<= 1) {
            float m2 = __shfl_xor(mx, off);
            float s2 = __shfl_xor(sm, off);
            float nm = fmaxf(mx, m2);
            sm = sm * expf(mx - nm) + s2 * expf(m2 - nm);
            mx = nm;
        }
        if (sub == 0) {
            float lse = mx + logf(sm);
            if (ent & 0x10000u) {
                int lab = (int)((ent >> 17) & 0xFFu);
                float ce = lse - cls[row * CC + lab];   // L1-hot reread
                float pt = expf(-ce);
                float o  = 1.0f - pt;
                aP += (lab > 0 ? 0.25f : 0.75f) * o * o * ce;
            } else {
                float ce = lse - v0.x;
                float pt = expf(-ce);
                float o  = 1.0f - pt;
                aN += 0.9f * o * o * o * ce;
            }
        }
    }

    #pragma unroll
    for (int off = 32; off > 0; off >>= 1) {
        aP += __shfl_down(aP, off);
        aN += __shfl_down(aN, off);
    }
    __shared__ float wp[4], wn[4];
    __shared__ int sh_last;
    const int lane = threadIdx.x & 63, wave = threadIdx.x >> 6;
    if (lane == 0) { wp[wave] = aP; wn[wave] = aN; }
    __syncthreads();
    if (threadIdx.x == 0) {
        atomicAdd(&accum[b * 3 + 0], wp[0] + wp[1] + wp[2] + wp[3]);
        atomicAdd(&accum[b * 3 + 1], wn[0] + wn[1] + wn[2] + wn[3]);
        __threadfence();
        sh_last = atomicAdd(doneF, 1);
    }
    __syncthreads();
    if (sh_last == (int)(gridDim.x * gridDim.y) - 1 && threadIdx.x == 0) {
        // finalize (absorbed k_finalize)
        float clsf = 0.0f, regf = 0.0f;
        int tp = 0;
        for (int bb = 0; bb < BB; ++bb) {
            float cp = accum[bb * 3 + 0];
            float cn = accum[bb * 3 + 1];
            float rs = accum[bb * 3 + 2];
            int np = numpos[bb], kk = knum[bb];
            int ts = np + kk; if (ts < 1) ts = 1;
            clsf += (cp + cn) / (float)ts;
            regf += rs / ((float)np + 1e-6f);
            tp += np;
        }
        clsf *= (1.0f / BB);
        regf *= (1.0f / BB);
        float reg_final = (tp > 0) ? regf : 0.0f;
        float rw = fminf(1.0f, (float)tp / (100.0f * BB));
        out[0] = clsf + rw * reg_final;
        out[1] = clsf;
        out[2] = reg_final;
        out[3] = (float)tp;
    }
}

extern "C" void kernel_launch(void* const* d_in, const int* in_sizes, int n_in,
                              void* d_out, int out_size, void* d_ws, size_t ws_size,
                              hipStream_t stream)
{
    const float* cls     = (const float*)d_in[0];
    const float* reg     = (const float*)d_in[1];
    const float* anchors = (const float*)d_in[2];
    const float* tboxes  = (const float*)d_in[3];
    const int*   tlabels = (const int*)d_in[4];

    const size_t PL = (size_t)BB * NN * 4;   // one float plane = 2 MB
    char* ws = (char*)d_ws;
    float*    miou = (float*)(ws);                         // 2 MB
    unsigned* list = (unsigned*)(ws + PL);                 // 2 MB
    unsigned char* mask = (unsigned char*)(ws + 2 * PL);   // 512 KB (fallback only)
    unsigned* tieU = (unsigned*)(ws + 2 * PL + PL / 4);    // 128 KB
    int*      tieI = (int*)(ws + 2 * PL + PL / 4 + (size_t)BB * TIECAP * 4); // 128 KB
    char* Z = ws + 2 * PL + PL / 4 + 2 * (size_t)BB * TIECAP * 4;
    unsigned* gHist    = (unsigned*)Z;                     // 16 KB
    unsigned* fineHist = (unsigned*)(Z + 16384);           // 64 KB
    char* ctr = Z + 16384 + 65536;
    int*   posCnt  = (int*)(ctr);          // 32 B
    int*   listCnt = (int*)(ctr + 32);
    int*   tieCnt  = (int*)(ctr + 64);
    int*   numpos  = (int*)(ctr + 96);
    int*   knum    = (int*)(ctr + 128);
    float* accum   = (float*)(ctr + 160);  // 24 floats (96 B)
    int*   doneC   = (int*)(ctr + 256);    // 32 B
    int*   doneF   = (int*)(ctr + 288);    // 4 B
    float* out     = (float*)d_out;

    // gHist + fineHist + all counters/accum/done must start zeroed
    hipMemsetAsync(Z, 0, 16384 + 65536 + 384, stream);

    k_prep<<<dim3(NN / 256, BB), 256, 0, stream>>>(reg, anchors, tboxes,
                                                   miou, gHist, posCnt);
    k_finehist<<<dim3(32, BB), 256, 0, stream>>>(miou, gHist, posCnt, fineHist);
    k_compact<<<dim3(32, BB), 256, 0, stream>>>(reg, anchors, tboxes, tlabels,
                                                miou, gHist, fineHist, posCnt,
                                                list, listCnt, tieU, tieI, tieCnt,
                                                doneC, numpos, knum, accum);
    k_fallback<<<BB, 1024, 0, stream>>>(reg, anchors, tboxes, tlabels, miou, mask,
                                        posCnt, list, listCnt, numpos, knum, accum);
    k_cls2<<<dim3(256, BB), 256, 0, stream>>>(cls, list, listCnt, accum,
                                              numpos, knum, doneF, out);
}

// Round 6
// 283.692 us; speedup vs baseline: 1.3297x; 1.3297x over previous
//
#include <hip/hip_runtime.h>
#include <math.h>

#define BB 8
#define NN 65536
#define CC 80
#define TT 32
#define MINPOS 16
#define TIECAP 4096

__device__ __forceinline__ float frcp(float x) { return __builtin_amdgcn_rcpf(x); }

// posCnt[b] == sum of gHist[b][504..511]  (0.5f == 0x3F000000 -> bin 504;
// miou <= 1.0f -> bin <= 508). Avoids hot-line global atomics entirely.
__device__ __forceinline__ int pc_from_hist(const unsigned* gHist, int b)
{
    int s = 0;
    #pragma unroll
    for (int j = 504; j < 512; ++j) s += (int)gHist[b * 512 + j];
    return s;
}

// ------------------------------------------------------------------
// K1 (k_prep): decode + IoU max + coarse 512-bin hist of miou float
// bits [31:21]. Grid (N/256, B). NO global hot-line atomics (posCnt
// derived from gHist by consumers).
// ------------------------------------------------------------------
__global__ __launch_bounds__(256) void k_prep(
    const float* __restrict__ reg, const float* __restrict__ anchors,
    const float* __restrict__ tboxes,
    float* __restrict__ miou_out, unsigned* __restrict__ gHist)
{
    const int b   = blockIdx.y;
    const int tid = threadIdx.x;
    const int a   = blockIdx.x * 256 + tid;

    __shared__ float4 tb[TT];
    __shared__ float  tareaE[TT];
    __shared__ unsigned lh[512];

    if (tid < TT) {
        float4 t = ((const float4*)(tboxes + (size_t)b * TT * 4))[tid];
        tb[tid] = t;
        tareaE[tid] = (t.z - t.x) * (t.w - t.y) + 1e-6f;
    }
    lh[tid] = 0u; lh[tid + 256] = 0u;
    __syncthreads();

    float4 r  = ((const float4*)reg)[(size_t)b * NN + a];
    float4 an = ((const float4*)anchors)[a];
    float aw = an.z - an.x, ah = an.w - an.y;
    float acx = an.x + 0.5f * aw, acy = an.y + 0.5f * ah;
    float cx = r.x * aw + acx, cy = r.y * ah + acy;
    float w = expf(r.z) * aw, hh = expf(r.w) * ah;
    float dx0 = cx - 0.5f * w, dy0 = cy - 0.5f * hh;
    float dx1 = cx + 0.5f * w, dy1 = cy + 0.5f * hh;
    float areaA = (dx1 - dx0) * (dy1 - dy0);

    float mi = 0.0f;
    #pragma unroll 8
    for (int t = 0; t < TT; ++t) {
        float4 bx = tb[t];
        float ltx = fmaxf(dx0, bx.x), lty = fmaxf(dy0, bx.y);
        float rbx = fminf(dx1, bx.z), rby = fminf(dy1, bx.w);
        float iw = fmaxf(rbx - ltx, 0.0f), ih = fmaxf(rby - lty, 0.0f);
        float inter = iw * ih;
        float den = areaA + tareaE[t] - inter;
        float iou = inter * frcp(den);
        mi = fmaxf(mi, iou);
    }

    miou_out[(size_t)b * NN + a] = mi;
    atomicAdd(&lh[__float_as_uint(mi) >> 21], 1u);
    __syncthreads();

    if (lh[tid])       atomicAdd(&gHist[b * 512 + tid],       lh[tid]);
    if (lh[tid + 256]) atomicAdd(&gHist[b * 512 + tid + 256], lh[tid + 256]);
}

// ------------------------------------------------------------------
// scan over an LDS histogram: find bin d s.t. (count strictly above d)
// < need <= (count above + h[d]). sh_s[2]=need on entry; writes
// sh_s[0]=bin, sh_s[1]=count strictly above. Proven R1..R5.
// ------------------------------------------------------------------
__device__ __forceinline__ void scan_hist64(unsigned* hist, int NB, int tid, int* sh_s)
{
    if (tid < 64) {
        const int cs = NB / 64;
        const int base = tid * cs;
        int csum = 0;
        for (int j = 0; j < cs; ++j) csum += (int)hist[base + j];
        int sfx = csum;
        #pragma unroll
        for (int off = 1; off < 64; off <<= 1) {
            int o = __shfl_down(sfx, off);
            if (tid + off < 64) sfx += o;
        }
        const int excl = sfx - csum;
        const int need = sh_s[2];
        int acc = excl;
        for (int j = cs - 1; j >= 0; --j) {
            int hcnt = (int)hist[base + j];
            int S = acc + hcnt;
            if (acc < need && S >= need) { sh_s[0] = base + j; sh_s[1] = acc; }
            acc = S;
        }
    }
}

// ------------------------------------------------------------------
// K2 (k_finehist): grid-parallel fine histogram (bits [20:10]) of the
// values inside the coarse pivot bin. Grid (32, B).
// ------------------------------------------------------------------
__global__ __launch_bounds__(256) void k_finehist(
    const float* __restrict__ miou_all, const unsigned* __restrict__ gHist,
    unsigned* __restrict__ fineHist)
{
    const int b = blockIdx.y;
    const int tid = threadIdx.x;

    __shared__ unsigned hist[512];
    __shared__ int sh_s[3];
    __shared__ int sh_pc;
    if (tid == 0) sh_pc = pc_from_hist(gHist, b);
    hist[tid]       = (tid <= 503)       ? gHist[b * 512 + tid]       : 0u;
    hist[tid + 256] = (tid + 256 <= 503) ? gHist[b * 512 + tid + 256] : 0u;
    __syncthreads();
    const int pc = sh_pc;
    if (pc < MINPOS) return;                    // fallback path handles it
    const int np = pc;
    int kk = NN - np; if (4 * np < kk) kk = 4 * np;
    if (tid == 0) sh_s[2] = kk;
    __syncthreads();
    scan_hist64(hist, 512, tid, sh_s);
    __syncthreads();
    const unsigned pivotBin = (unsigned)sh_s[0];

    const float* miou = miou_all + (size_t)b * NN;
    const int base = blockIdx.x * 2048;
    for (int i = base + tid; i < base + 2048; i += 256) {
        unsigned u = __float_as_uint(miou[i]);
        if ((u >> 21) == pivotBin)
            atomicAdd(&fineHist[b * 2048 + ((u >> 10) & 2047u)], 1u);
    }
}

// ------------------------------------------------------------------
// K3 (k_compact): grid-parallel selection + compaction. Grid (32, B).
// (R4-proven structure; pc now derived from gHist.)
// ------------------------------------------------------------------
__global__ __launch_bounds__(256) void k_compact(
    const float* __restrict__ reg, const float* __restrict__ anchors,
    const float* __restrict__ tboxes, const int* __restrict__ tlabels,
    const float* __restrict__ miou_all,
    const unsigned* __restrict__ gHist, const unsigned* __restrict__ fineHist,
    unsigned* __restrict__ list_all, int* __restrict__ listCnt,
    unsigned* __restrict__ tieU_all, int* __restrict__ tieI_all,
    int* __restrict__ tieCnt,
    int* __restrict__ numpos, int* __restrict__ knum, float* __restrict__ accum)
{
    const int b = blockIdx.y;
    const int tid = threadIdx.x;

    __shared__ float4 tb[TT];
    __shared__ float  tareaE[TT];
    __shared__ int    tl[TT];
    __shared__ unsigned hist[2048];
    __shared__ unsigned lbuf[2048];
    __shared__ int sh_s[3];
    __shared__ int sh_pc, sh_cnt, sh_base;
    __shared__ float wred[4];

    if (tid == 0) { sh_pc = pc_from_hist(gHist, b); sh_cnt = 0; }
    if (tid < TT) {
        float4 t = ((const float4*)(tboxes + (size_t)b * TT * 4))[tid];
        tb[tid] = t;
        tareaE[tid] = (t.z - t.x) * (t.w - t.y) + 1e-6f;
        tl[tid] = tlabels[b * TT + tid];
    }
    hist[tid]       = (tid <= 503)       ? gHist[b * 512 + tid]       : 0u;
    hist[tid + 256] = (tid + 256 <= 503) ? gHist[b * 512 + tid + 256] : 0u;
    __syncthreads();
    const int pc = sh_pc;
    if (pc < MINPOS) return;                    // fallback path handles it
    const int np = pc;
    int kk = NN - np; if (4 * np < kk) kk = 4 * np;
    if (tid == 0) sh_s[2] = kk;
    __syncthreads();
    scan_hist64(hist, 512, tid, sh_s);
    __syncthreads();
    const unsigned pivotBin = (unsigned)sh_s[0];
    const int needB = kk - sh_s[1];
    __syncthreads();
    for (int k = tid; k < 2048; k += 256) hist[k] = fineHist[b * 2048 + k];
    if (tid == 0) sh_s[2] = needB;
    __syncthreads();
    scan_hist64(hist, 2048, tid, sh_s);
    __syncthreads();
    const unsigned pivot22 = (pivotBin << 11) | (unsigned)sh_s[0];

    float accR = 0.0f;
    const float* miou = miou_all + (size_t)b * NN;
    const int base = blockIdx.x * 2048;
    for (int i = base + tid; i < base + 2048; i += 256) {
        float v = miou[i];
        unsigned u = __float_as_uint(v);
        if (v >= 0.5f) {
            // recompute argmax (bit-identical IoU to k_prep) + sl1 + label
            float4 r  = ((const float4*)reg)[(size_t)b * NN + i];
            float4 an = ((const float4*)anchors)[i];
            float aw = an.z - an.x, ah = an.w - an.y;
            float acx = an.x + 0.5f * aw, acy = an.y + 0.5f * ah;
            float cx = r.x * aw + acx, cy = r.y * ah + acy;
            float w = expf(r.z) * aw, hh2 = expf(r.w) * ah;
            float dx0 = cx - 0.5f * w, dy0 = cy - 0.5f * hh2;
            float dx1 = cx + 0.5f * w, dy1 = cy + 0.5f * hh2;
            float areaA = (dx1 - dx0) * (dy1 - dy0);
            float mi = 0.0f; int mix = 0;
            #pragma unroll 8
            for (int t = 0; t < TT; ++t) {
                float4 bx = tb[t];
                float ltx = fmaxf(dx0, bx.x), lty = fmaxf(dy0, bx.y);
                float rbx = fminf(dx1, bx.z), rby = fminf(dy1, bx.w);
                float iw = fmaxf(rbx - ltx, 0.0f), ih = fmaxf(rby - lty, 0.0f);
                float inter = iw * ih;
                float den = areaA + tareaE[t] - inter;
                float iou = inter * frcp(den);
                if (iou > mi) { mi = iou; mix = t; }
            }
            float4 gt = tb[mix];
            float gw = gt.z - gt.x, gh = gt.w - gt.y;
            float gcx = gt.x + 0.5f * gw, gcy = gt.y + 0.5f * gh;
            float t0 = (gcx - acx) / (aw + 1e-6f);
            float t1 = (gcy - acy) / (ah + 1e-6f);
            float t2 = logf(gw / (aw + 1e-6f));
            float t3 = logf(gh / (ah + 1e-6f));
            float d0 = fabsf(r.x - t0), d1 = fabsf(r.y - t1);
            float d2 = fabsf(r.z - t2), d3 = fabsf(r.w - t3);
            accR += (d0 < 1.0f ? 0.5f * d0 * d0 : d0 - 0.5f)
                  + (d1 < 1.0f ? 0.5f * d1 * d1 : d1 - 0.5f)
                  + (d2 < 1.0f ? 0.5f * d2 * d2 : d2 - 0.5f)
                  + (d3 < 1.0f ? 0.5f * d3 * d3 : d3 - 0.5f);
            int t4 = atomicAdd(&sh_cnt, 1);
            lbuf[t4] = (unsigned)i | 0x10000u | ((unsigned)tl[mix] << 17);
        } else {
            unsigned p = u >> 10;
            if (p > pivot22) {
                int t = atomicAdd(&sh_cnt, 1);
                lbuf[t] = (unsigned)i;
            } else if (p == pivot22) {
                int t = atomicAdd(&tieCnt[b], 1);
                if (t < TIECAP) {
                    tieU_all[b * TIECAP + t] = u;
                    tieI_all[b * TIECAP + t] = i;
                }
            }
        }
    }
    __syncthreads();
    const int cnt = sh_cnt;
    if (tid == 0) sh_base = atomicAdd(&listCnt[b], cnt);
    __syncthreads();
    unsigned* list = list_all + (size_t)b * NN;
    for (int k = tid; k < cnt; k += 256) list[sh_base + k] = lbuf[k];

    #pragma unroll
    for (int off = 32; off > 0; off >>= 1) accR += __shfl_down(accR, off);
    const int lane = tid & 63, wave = tid >> 6;
    if (lane == 0) wred[wave] = accR;
    __syncthreads();
    if (tid == 0) {
        atomicAdd(&accum[b * 3 + 2], wred[0] + wred[1] + wred[2] + wred[3]);
        if (blockIdx.x == 0) { numpos[b] = np; knum[b] = kk; }
    }
}

// ------------------------------------------------------------------
// K4 (k_tierank): rank the few pivot-bin ties (value desc, index asc),
// append accepted negatives. Grid (B) x 256. (R4-proven.)
// ------------------------------------------------------------------
__global__ __launch_bounds__(256) void k_tierank(
    const unsigned* __restrict__ gHist, const unsigned* __restrict__ fineHist,
    const unsigned* __restrict__ tieU_all, const int* __restrict__ tieI_all,
    const int* __restrict__ tieCnt,
    unsigned* __restrict__ list_all, int* __restrict__ listCnt)
{
    const int b = blockIdx.x;
    const int tid = threadIdx.x;

    __shared__ unsigned hist[2048];
    __shared__ int sh_s[3];
    __shared__ int sh_pc;
    __shared__ unsigned tu[TIECAP];
    __shared__ int ti[TIECAP];

    if (tid == 0) sh_pc = pc_from_hist(gHist, b);
    hist[tid]       = (tid <= 503)       ? gHist[b * 512 + tid]       : 0u;
    hist[tid + 256] = (tid + 256 <= 503) ? gHist[b * 512 + tid + 256] : 0u;
    __syncthreads();
    const int pc = sh_pc;
    if (pc < MINPOS) return;
    const int np = pc;
    int kk = NN - np; if (4 * np < kk) kk = 4 * np;
    if (tid == 0) sh_s[2] = kk;
    __syncthreads();
    scan_hist64(hist, 512, tid, sh_s);
    __syncthreads();
    const int needB = kk - sh_s[1];
    __syncthreads();
    for (int k = tid; k < 2048; k += 256) hist[k] = fineHist[b * 2048 + k];
    if (tid == 0) sh_s[2] = needB;
    __syncthreads();
    scan_hist64(hist, 2048, tid, sh_s);
    __syncthreads();
    const int rem = needB - sh_s[1];     // ties to accept

    int c = tieCnt[b]; if (c > TIECAP) c = TIECAP;
    for (int k = tid; k < c; k += 256) {
        tu[k] = tieU_all[b * TIECAP + k];
        ti[k] = tieI_all[b * TIECAP + k];
    }
    __syncthreads();
    unsigned* list = list_all + (size_t)b * NN;
    for (int t = tid; t < c; t += 256) {
        unsigned ut = tu[t]; int it = ti[t];
        int rank = 0;
        for (int j = 0; j < c; ++j) {
            unsigned uj = tu[j]; int ij = ti[j];
            rank += (uj > ut || (uj == ut && ij < it)) ? 1 : 0;
        }
        if (rank < rem) {
            int p = atomicAdd(&listCnt[b], 1);
            list[p] = (unsigned)it;
        }
    }
}

// R1-proven 3-round radix select (fallback path only).
__device__ __forceinline__ void radix_select(
    const float* __restrict__ vals, const unsigned char* __restrict__ mask,
    int mode, int kk, int tid,
    unsigned* hist, int* sh_s, unsigned* sh_u)
{
    if (tid == 0) { sh_u[0] = 0u; sh_u[1] = 0u; sh_s[2] = kk; }
    __syncthreads();
    #pragma unroll
    for (int rnd = 0; rnd < 3; ++rnd) {
        const int sh = (rnd == 0) ? 21 : ((rnd == 1) ? 10 : 0);
        const int NB = (rnd == 2) ? 1024 : 2048;
        hist[tid] = 0u; hist[tid + 1024] = 0u;
        __syncthreads();
        const unsigned pref = sh_u[0], pmask = sh_u[1];
        for (int i = tid; i < NN; i += 1024) {
            bool c = (mode == 0) ? true : (mask[i] != (unsigned char)1);
            if (c) {
                unsigned u = __float_as_uint(vals[i]);
                if ((u & pmask) == pref)
                    atomicAdd(&hist[(u >> sh) & (unsigned)(NB - 1)], 1u);
            }
        }
        __syncthreads();
        scan_hist64(hist, NB, tid, sh_s);
        __syncthreads();
        if (tid == 0) {
            sh_u[0] |= ((unsigned)sh_s[0]) << sh;
            sh_u[1] |= ((unsigned)(NB - 1)) << sh;
            sh_s[2] -= sh_s[1];
        }
        __syncthreads();
    }
}

// ------------------------------------------------------------------
// K5 (k_fallback): full slow path, only if pc < MINPOS (never hit with
// this data — early-returns). Grid (B) x 1024.
// ------------------------------------------------------------------
__global__ __launch_bounds__(1024) void k_fallback(
    const float* __restrict__ reg, const float* __restrict__ anchors,
    const float* __restrict__ tboxes, const int* __restrict__ tlabels,
    const float* __restrict__ miou_all, unsigned char* __restrict__ mask_all,
    const unsigned* __restrict__ gHist,
    unsigned* __restrict__ list_all, int* __restrict__ listCnt,
    int* __restrict__ numpos, int* __restrict__ knum, float* __restrict__ accum)
{
    const int b = blockIdx.x;
    const int tid = threadIdx.x;

    __shared__ int sh_pc;
    if (tid == 0) sh_pc = pc_from_hist(gHist, b);
    __syncthreads();
    if (sh_pc >= MINPOS) return;

    const float* miou = miou_all + (size_t)b * NN;
    unsigned char* mask = mask_all + (size_t)b * NN;
    unsigned* list = list_all + (size_t)b * NN;

    __shared__ float4 tb[TT];
    __shared__ float  tareaE[TT];
    __shared__ int    tl[TT];
    __shared__ unsigned hist[2048];
    __shared__ int sh_s[3];
    __shared__ unsigned sh_u[2];
    __shared__ int wtot[16];
    __shared__ int sh_ties;
    __shared__ float wred[16];

    if (tid < TT) {
        float4 t = ((const float4*)(tboxes + (size_t)b * TT * 4))[tid];
        tb[tid] = t;
        tareaE[tid] = (t.z - t.x) * (t.w - t.y) + 1e-6f;
        tl[tid] = tlabels[b * TT + tid];
    }
    __syncthreads();

    radix_select(miou, mask, 0, MINPOS, tid, hist, sh_s, sh_u);
    {
        const unsigned vb = sh_u[0];
        const int rem = sh_s[2];
        if (tid == 0) sh_ties = 0;
        __syncthreads();
        for (int base = 0; base < NN; base += 1024) {
            const int i = base + tid;
            const unsigned u = __float_as_uint(miou[i]);
            const bool tie = (u == vb);
            unsigned long long bal = __ballot(tie);
            const int wave = tid >> 6, lane = tid & 63;
            if (lane == 0) wtot[wave] = __popcll(bal);
            __syncthreads();
            int wexcl = 0;
            for (int wv = 0; wv < wave; ++wv) wexcl += wtot[wv];
            const int myexcl = sh_ties + wexcl + __popcll(bal & ((1ull << lane) - 1ull));
            const bool sel = (u > vb) || (tie && myexcl < rem);
            mask[i] = sel ? (unsigned char)1 : (unsigned char)0;
            __syncthreads();
            if (tid == 0) { int ts = 0; for (int wv = 0; wv < 16; ++wv) ts += wtot[wv]; sh_ties += ts; }
            __syncthreads();
        }
    }
    const int np = MINPOS;
    int kk = NN - np; if (4 * np < kk) kk = 4 * np;
    radix_select(miou, mask, 2, kk, tid, hist, sh_s, sh_u);
    {
        const unsigned vb = sh_u[0];
        const int rem = sh_s[2];
        if (tid == 0) sh_ties = 0;
        __syncthreads();
        for (int base = 0; base < NN; base += 1024) {
            const int i = base + tid;
            const unsigned u = __float_as_uint(miou[i]);
            const bool pos = (mask[i] == (unsigned char)1);
            const bool cand = !pos;
            const bool tie = cand && (u == vb);
            unsigned long long bal = __ballot(tie);
            const int wave = tid >> 6, lane = tid & 63;
            if (lane == 0) wtot[wave] = __popcll(bal);
            __syncthreads();
            int wexcl = 0;
            for (int wv = 0; wv < wave; ++wv) wexcl += wtot[wv];
            const int myexcl = sh_ties + wexcl + __popcll(bal & ((1ull << lane) - 1ull));
            const bool neg = cand && ((u > vb) || (tie && myexcl < rem));
            mask[i] = pos ? (unsigned char)1 : (neg ? (unsigned char)2 : (unsigned char)0);
            __syncthreads();
            if (tid == 0) { int ts = 0; for (int wv = 0; wv < 16; ++wv) ts += wtot[wv]; sh_ties += ts; }
            __syncthreads();
        }
    }

    float accR = 0.0f;
    for (int i = tid; i < NN; i += 1024) {
        unsigned char m = mask[i];
        if (m == (unsigned char)1) {
            float4 r  = ((const float4*)reg)[(size_t)b * NN + i];
            float4 an = ((const float4*)anchors)[i];
            float aw = an.z - an.x, ah = an.w - an.y;
            float acx = an.x + 0.5f * aw, acy = an.y + 0.5f * ah;
            float cx = r.x * aw + acx, cy = r.y * ah + acy;
            float w = expf(r.z) * aw, hh2 = expf(r.w) * ah;
            float dx0 = cx - 0.5f * w, dy0 = cy - 0.5f * hh2;
            float dx1 = cx + 0.5f * w, dy1 = cy + 0.5f * hh2;
            float areaA = (dx1 - dx0) * (dy1 - dy0);
            float mi = 0.0f; int mix = 0;
            for (int t = 0; t < TT; ++t) {
                float4 bx = tb[t];
                float ltx = fmaxf(dx0, bx.x), lty = fmaxf(dy0, bx.y);
                float rbx = fminf(dx1, bx.z), rby = fminf(dy1, bx.w);
                float iw = fmaxf(rbx - ltx, 0.0f), ih = fmaxf(rby - lty, 0.0f);
                float inter = iw * ih;
                float den = areaA + tareaE[t] - inter;
                float iou = inter * frcp(den);
                if (iou > mi) { mi = iou; mix = t; }
            }
            float4 gt = tb[mix];
            float gw = gt.z - gt.x, gh = gt.w - gt.y;
            float gcx = gt.x + 0.5f * gw, gcy = gt.y + 0.5f * gh;
            float t0 = (gcx - acx) / (aw + 1e-6f);
            float t1 = (gcy - acy) / (ah + 1e-6f);
            float t2 = logf(gw / (aw + 1e-6f));
            float t3 = logf(gh / (ah + 1e-6f));
            float d0 = fabsf(r.x - t0), d1 = fabsf(r.y - t1);
            float d2 = fabsf(r.z - t2), d3 = fabsf(r.w - t3);
            accR += (d0 < 1.0f ? 0.5f * d0 * d0 : d0 - 0.5f)
                  + (d1 < 1.0f ? 0.5f * d1 * d1 : d1 - 0.5f)
                  + (d2 < 1.0f ? 0.5f * d2 * d2 : d2 - 0.5f)
                  + (d3 < 1.0f ? 0.5f * d3 * d3 : d3 - 0.5f);
            int t = atomicAdd(&listCnt[b], 1);
            list[t] = (unsigned)i | 0x10000u | ((unsigned)tl[mix] << 17);
        } else if (m == (unsigned char)2) {
            int t = atomicAdd(&listCnt[b], 1);
            list[t] = (unsigned)i;
        }
    }

    #pragma unroll
    for (int off = 32; off > 0; off >>= 1) accR += __shfl_down(accR, off);
    const int lane = tid & 63, wave = tid >> 6;
    if (lane == 0) wred[wave] = accR;
    __syncthreads();
    if (tid == 0) {
        float sR = 0.0f;
        for (int w = 0; w < 16; ++w) sR += wred[w];
        accum[b * 3 + 2] = sR;
        numpos[b] = np;
        knum[b] = kk;
    }
}

// ------------------------------------------------------------------
// K6 (k_cls2): gather logsumexp ONLY for selected anchors. Grid (128,B).
// NO global atomics: each block stores its partial to a unique slot.
// ------------------------------------------------------------------
__global__ __launch_bounds__(256) void k_cls2(
    const float* __restrict__ cls, const unsigned* __restrict__ list_all,
    const int* __restrict__ listCnt,
    float* __restrict__ partP, float* __restrict__ partN)
{
    const int b   = blockIdx.y;
    const int n   = listCnt[b];
    const int al  = threadIdx.x >> 2;
    const int sub = threadIdx.x & 3;
    const unsigned* list = list_all + (size_t)b * NN;

    float aP = 0.0f, aN = 0.0f;
    for (int e = blockIdx.x * 64 + al; e < n; e += gridDim.x * 64) {
        unsigned ent = list[e];
        int a = (int)(ent & 0xFFFFu);
        size_t row = (size_t)b * NN + a;
        const float4* rowp = (const float4*)(cls + row * CC);
        float4 v0 = rowp[sub];
        float4 v1 = rowp[sub + 4];
        float4 v2 = rowp[sub + 8];
        float4 v3 = rowp[sub + 12];
        float4 v4 = rowp[sub + 16];
        float mx = fmaxf(fmaxf(fmaxf(v0.x, v0.y), fmaxf(v0.z, v0.w)),
                   fmaxf(fmaxf(fmaxf(v1.x, v1.y), fmaxf(v1.z, v1.w)),
                   fmaxf(fmaxf(fmaxf(v2.x, v2.y), fmaxf(v2.z, v2.w)),
                   fmaxf(fmaxf(fmaxf(v3.x, v3.y), fmaxf(v3.z, v3.w)),
                         fmaxf(fmaxf(v4.x, v4.y), fmaxf(v4.z, v4.w))))));
        float sm = expf(v0.x - mx) + expf(v0.y - mx) + expf(v0.z - mx) + expf(v0.w - mx)
                 + expf(v1.x - mx) + expf(v1.y - mx) + expf(v1.z - mx) + expf(v1.w - mx)
                 + expf(v2.x - mx) + expf(v2.y - mx) + expf(v2.z - mx) + expf(v2.w - mx)
                 + expf(v3.x - mx) + expf(v3.y - mx) + expf(v3.z - mx) + expf(v3.w - mx)
                 + expf(v4.x - mx) + expf(v4.y - mx) + expf(v4.z - mx) + expf(v4.w - mx);
        #pragma unroll
        for (int off = 1; off < 4; off <<= 1) {
            float m2 = __shfl_xor(mx, off);
            float s2 = __shfl_xor(sm, off);
            float nm = fmaxf(mx, m2);
            sm = sm * expf(mx - nm) + s2 * expf(m2 - nm);
            mx = nm;
        }
        if (sub == 0) {
            float lse = mx + logf(sm);
            if (ent & 0x10000u) {
                int lab = (int)((ent >> 17) & 0xFFu);
                float ce = lse - cls[row * CC + lab];   // L1-hot reread
                float pt = expf(-ce);
                float o  = 1.0f - pt;
                aP += (lab > 0 ? 0.25f : 0.75f) * o * o * ce;
            } else {
                float ce = lse - v0.x;
                float pt = expf(-ce);
                float o  = 1.0f - pt;
                aN += 0.9f * o * o * o * ce;
            }
        }
    }

    #pragma unroll
    for (int off = 32; off > 0; off >>= 1) {
        aP += __shfl_down(aP, off);
        aN += __shfl_down(aN, off);
    }
    __shared__ float wp[4], wn[4];
    const int lane = threadIdx.x & 63, wave = threadIdx.x >> 6;
    if (lane == 0) { wp[wave] = aP; wn[wave] = aN; }
    __syncthreads();
    if (threadIdx.x == 0) {
        // unique slot per block — plain stores, zero contention
        partP[b * 128 + blockIdx.x] = wp[0] + wp[1] + wp[2] + wp[3];
        partN[b * 128 + blockIdx.x] = wn[0] + wn[1] + wn[2] + wn[3];
    }
}

// ------------------------------------------------------------------
// K7 (k_finalize): sum per-block partials (2 KB, L2-hot) + 4 scalars.
// One wave.
// ------------------------------------------------------------------
__global__ __launch_bounds__(64) void k_finalize(
    const float* __restrict__ accum,
    const float* __restrict__ partP, const float* __restrict__ partN,
    const int* __restrict__ numpos, const int* __restrict__ knum,
    float* __restrict__ out)
{
    const int lane = threadIdx.x;    // 64 threads, single wave
    float clsf = 0.0f, regf = 0.0f;
    int tp = 0;
    for (int b = 0; b < BB; ++b) {
        float p = partP[b * 128 + lane] + partP[b * 128 + 64 + lane];
        float q = partN[b * 128 + lane] + partN[b * 128 + 64 + lane];
        #pragma unroll
        for (int off = 32; off > 0; off >>= 1) {
            p += __shfl_down(p, off);
            q += __shfl_down(q, off);
        }
        if (lane == 0) {
            int np = numpos[b], kk = knum[b];
            int ts = np + kk; if (ts < 1) ts = 1;
            clsf += (p + q) / (float)ts;
            regf += accum[b * 3 + 2] / ((float)np + 1e-6f);
            tp += np;
        }
    }
    if (lane == 0) {
        clsf *= (1.0f / BB);
        regf *= (1.0f / BB);
        float reg_final = (tp > 0) ? regf : 0.0f;
        float rw = fminf(1.0f, (float)tp / (100.0f * BB));
        out[0] = clsf + rw * reg_final;
        out[1] = clsf;
        out[2] = reg_final;
        out[3] = (float)tp;
    }
}

extern "C" void kernel_launch(void* const* d_in, const int* in_sizes, int n_in,
                              void* d_out, int out_size, void* d_ws, size_t ws_size,
                              hipStream_t stream)
{
    const float* cls     = (const float*)d_in[0];
    const float* reg     = (const float*)d_in[1];
    const float* anchors = (const float*)d_in[2];
    const float* tboxes  = (const float*)d_in[3];
    const int*   tlabels = (const int*)d_in[4];

    const size_t PL = (size_t)BB * NN * 4;   // one float plane = 2 MB
    char* ws = (char*)d_ws;
    float*    miou = (float*)(ws);                         // 2 MB
    unsigned* list = (unsigned*)(ws + PL);                 // 2 MB
    unsigned char* mask = (unsigned char*)(ws + 2 * PL);   // 512 KB (fallback only)
    unsigned* tieU = (unsigned*)(ws + 2 * PL + PL / 4);    // 128 KB
    int*      tieI = (int*)(ws + 2 * PL + PL / 4 + (size_t)BB * TIECAP * 4); // 128 KB
    char* Z = ws + 2 * PL + PL / 4 + 2 * (size_t)BB * TIECAP * 4;
    unsigned* gHist    = (unsigned*)Z;                     // 16 KB
    unsigned* fineHist = (unsigned*)(Z + 16384);           // 64 KB
    char* ctr = Z + 16384 + 65536;
    int*   listCnt = (int*)(ctr);          // 32 B
    int*   tieCnt  = (int*)(ctr + 32);     // 32 B
    int*   numpos  = (int*)(ctr + 64);     // 32 B
    int*   knum    = (int*)(ctr + 96);     // 32 B
    float* accum   = (float*)(ctr + 128);  // 96 B
    float* partP   = (float*)(ctr + 256);  // 4 KB (written unconditionally)
    float* partN   = (float*)(ctr + 256 + 4096);  // 4 KB
    float* out     = (float*)d_out;

    // gHist + fineHist + counters + accum must start zeroed
    hipMemsetAsync(Z, 0, 16384 + 65536 + 256, stream);

    k_prep<<<dim3(NN / 256, BB), 256, 0, stream>>>(reg, anchors, tboxes,
                                                   miou, gHist);
    k_finehist<<<dim3(32, BB), 256, 0, stream>>>(miou, gHist, fineHist);
    k_compact<<<dim3(32, BB), 256, 0, stream>>>(reg, anchors, tboxes, tlabels,
                                                miou, gHist, fineHist,
                                                list, listCnt, tieU, tieI, tieCnt,
                                                numpos, knum, accum);
    k_tierank<<<BB, 256, 0, stream>>>(gHist, fineHist, tieU, tieI, tieCnt,
                                      list, listCnt);
    k_fallback<<<BB, 1024, 0, stream>>>(reg, anchors, tboxes, tlabels, miou, mask,
                                        gHist, list, listCnt, numpos, knum, accum);
    k_cls2<<<dim3(128, BB), 256, 0, stream>>>(cls, list, listCnt, partP, partN);
    k_finalize<<<1, 64, 0, stream>>>(accum, partP, partN, numpos, knum, out);
}